// Round 5
// baseline (4914.883 us; speedup 1.0000x reference)
//
#include <hip/hip_runtime.h>
#include <hip/hip_bf16.h>

// Kuramoto V2: B=8, N=2048, D=256, 50 steps.
//  1) normalize embeddings -> bf16 En
//  2) C = clip(En En^T, 0) -> fp8 e4m3 row-major (symmetric-store trick)
//  3) ONE persistent kernel runs all 50 steps: each block owns 16 rows of C,
//     staged to LDS once (XOR-swizzled) and reused all steps. Per-batch
//     producer/consumer sync via device-scope atomic counters (no launches).

constexpr int B = 8;
constexpr int N = 2048;
constexpr int D = 256;
constexpr int STEPS = 50;
constexpr float DT = 0.01f;
constexpr float K_OVER_N = 1.0f / 2048.0f;
constexpr float TWO_PI_F = 6.2831854820251465f; // float(2*pi)

using bf16x8 = __attribute__((ext_vector_type(8))) short;
using f32x4  = __attribute__((ext_vector_type(4))) float;

static __device__ __forceinline__ unsigned short f2bf(float f) {
    union { float f; unsigned int i; } v; v.f = f;
    unsigned int x = v.i;
    x += 0x7fffu + ((x >> 16) & 1u);   // RNE
    return (unsigned short)(x >> 16);
}
static __device__ __forceinline__ unsigned char f2fp8(float f) {
    return (unsigned char)(__builtin_amdgcn_cvt_pk_fp8_f32(f, f, 0, false) & 0xff);
}

// ---------------- normalize: one wave per row of 256 floats -> bf16 -------
__global__ void normalize_k(const float* __restrict__ emb,
                            unsigned short* __restrict__ En) {
    const int row  = blockIdx.x * 4 + (threadIdx.x >> 6);
    const int lane = threadIdx.x & 63;
    const float4 v = *(const float4*)(emb + (size_t)row * D + lane * 4);
    float ss = v.x * v.x + v.y * v.y + v.z * v.z + v.w * v.w;
    #pragma unroll
    for (int k = 32; k >= 1; k >>= 1) ss += __shfl_xor(ss, k);
    const float inv = 1.0f / fmaxf(sqrtf(ss), 1e-12f);
    ushort4 o;
    o.x = f2bf(v.x * inv); o.y = f2bf(v.y * inv);
    o.z = f2bf(v.z * inv); o.w = f2bf(v.w * inv);
    *(ushort4*)(En + (size_t)row * D + lane * 4) = o;
}

// ---------------- build C = clip(En En^T, 0) -> fp8 row-major --------------
// 64x64 block tile (wave = 32x32): low VGPR, 8192 blocks -> latency hiding.
// C/D frag: col = lane&15, row = (lane>>4)*4 + reg; store transposed (C sym).
__global__ __launch_bounds__(256) void build_c_k(const unsigned short* __restrict__ En,
                                                 unsigned char* __restrict__ C) {
    const int b = blockIdx.z;
    const unsigned short* Eb = En + (size_t)b * N * D;
    const int wid  = threadIdx.x >> 6;
    const int lane = threadIdx.x & 63;
    const int i_base = blockIdx.y * 64 + (wid >> 1) * 32;
    const int j_base = blockIdx.x * 64 + (wid & 1) * 32;
    const int fr = lane & 15;
    const int fk = (lane >> 4) * 8;

    f32x4 acc[2][2];
    #pragma unroll
    for (int m = 0; m < 2; ++m)
        #pragma unroll
        for (int n = 0; n < 2; ++n)
            acc[m][n] = (f32x4){0.f, 0.f, 0.f, 0.f};

    for (int k0 = 0; k0 < D; k0 += 32) {
        bf16x8 a[2], bv[2];
        #pragma unroll
        for (int m = 0; m < 2; ++m)
            a[m] = *(const bf16x8*)(Eb + (size_t)(i_base + m * 16 + fr) * D + k0 + fk);
        #pragma unroll
        for (int n = 0; n < 2; ++n)
            bv[n] = *(const bf16x8*)(Eb + (size_t)(j_base + n * 16 + fr) * D + k0 + fk);
        #pragma unroll
        for (int m = 0; m < 2; ++m)
            #pragma unroll
            for (int n = 0; n < 2; ++n)
                acc[m][n] = __builtin_amdgcn_mfma_f32_16x16x32_bf16(a[m], bv[n], acc[m][n], 0, 0, 0);
    }

    unsigned char* Cb = C + (size_t)b * N * N;
    const int orow = (lane >> 4) * 4;
    #pragma unroll
    for (int m = 0; m < 2; ++m)
        #pragma unroll
        for (int n = 0; n < 2; ++n) {
            int w = __builtin_amdgcn_cvt_pk_fp8_f32(fmaxf(acc[m][n][0], 0.f),
                                                    fmaxf(acc[m][n][1], 0.f), 0, false);
            w = __builtin_amdgcn_cvt_pk_fp8_f32(fmaxf(acc[m][n][2], 0.f),
                                                fmaxf(acc[m][n][3], 0.f), w, true);
            const int j = j_base + n * 16 + fr;
            const int i = i_base + m * 16 + orow;
            *(unsigned int*)(Cb + (size_t)j * N + i) = (unsigned int)w;
        }
}

// ---------------- init tables: fp8 cos/sin of theta0 -----------------------
// layout: tbl[b*4096 + 0..2047] = cos, tbl[b*4096 + 2048..4095] = sin
__global__ void init_tbl_k(const float* __restrict__ theta,
                           unsigned char* __restrict__ tbl) {
    const int idx = blockIdx.x * 256 + threadIdx.x;   // 0..B*N-1
    const int b = idx >> 11, i = idx & 2047;
    float s, c;
    sincosf(theta[idx], &s, &c);
    tbl[(size_t)b * 4096 + i] = f2fp8(c);
    tbl[(size_t)b * 4096 + 2048 + i] = f2fp8(s);
}

// ---------------- persistent 50-step kernel --------------------------------
// Block = 16 rows of one batch; 4 waves split K=2048 into 512 each.
// C rows live in LDS (XOR-swizzled) for all 50 steps. Per-batch barrier:
// monotonic counter cnt[b]; step s waits cnt[b] >= 128*s.
__global__ __launch_bounds__(256, 4) void fused_steps_k(
        const unsigned char* __restrict__ C,
        unsigned char* __restrict__ tbl0,   // step-even input tables
        unsigned char* __restrict__ tbl1,   // step-odd input tables
        const float* __restrict__ theta0,
        float* __restrict__ out,
        const float* __restrict__ omega,
        unsigned int* __restrict__ cnt) {
    __shared__ unsigned char s_C[16 * 2048];       // 32 KB, swizzled
    __shared__ unsigned char s_tbl[2080 + 2048];   // cos | pad32 | sin
    __shared__ f32x4 s_acc[4][8];
    __shared__ float s_th[16];

    const int rt = blockIdx.x;        // 16-row tile: rows rt*16..rt*16+15
    const int b  = blockIdx.y;
    const int t  = threadIdx.x;
    const int w = t >> 6, lane = t & 63;
    const int col = lane & 15, g = lane >> 4;

    // ---- stage my 16 C-rows into LDS once, XOR-swizzle 16B units ----
    {
        const unsigned char* src = C + ((size_t)b * N + rt * 16) * N;
        #pragma unroll
        for (int it = 0; it < 8; ++it) {
            const int idx = it * 256 + t;        // 16B-unit index, 0..2047
            const int row = idx >> 7;            // 128 units per 2048B row
            const int o   = (idx & 127) * 16;
            const uint4 v = *(const uint4*)(src + (size_t)row * N + o);
            *(uint4*)(s_C + row * 2048 + (o ^ ((row & 7) << 4))) = v;
        }
    }
    if (t < 16) s_th[t] = theta0[(size_t)b * N + rt * 16 + t];
    const float om = (t < 16) ? omega[rt * 16 + t] : 0.f;

    const unsigned char* Abase = s_C + col * 2048;
    const unsigned int sw = (unsigned)((col & 7) << 4);
    const int tblbase = (col == 1) ? 2080 : 0;    // col0 & col>=2 -> cos (bcast)
    const int o0 = w * 512 + g * 8;

    for (int s = 0; s < STEPS; ++s) {
        if (s > 0) {
            if (t == 0) {
                const unsigned int target = (unsigned)(128 * s);
                while (__hip_atomic_load(&cnt[b], __ATOMIC_RELAXED,
                                         __HIP_MEMORY_SCOPE_AGENT) < target)
                    __builtin_amdgcn_s_sleep(2);
                __builtin_amdgcn_fence(__ATOMIC_ACQUIRE, "agent");
            }
            __syncthreads();
        }
        // ---- stage this step's tables (4 KB) ----
        const unsigned char* tI = ((s & 1) ? tbl1 : tbl0) + (size_t)b * 4096;
        if (t < 128)
            *(uint4*)(s_tbl + t * 16) = *(const uint4*)(tI + t * 16);
        else {
            const int u = t - 128;
            *(uint4*)(s_tbl + 2080 + u * 16) = *(const uint4*)(tI + 2048 + u * 16);
        }
        __syncthreads();

        // ---- dual matvec via fp8 MFMA, A from swizzled LDS ----
        f32x4 acc = {0.f, 0.f, 0.f, 0.f};
        #pragma unroll
        for (int u = 0; u < 16; ++u) {
            const int o = o0 + u * 32;
            const long a = *(const long*)(Abase + (o ^ sw));
            long bv = *(const long*)(s_tbl + tblbase + o);
            bv = (col < 2) ? bv : 0L;
            acc = __builtin_amdgcn_mfma_f32_16x16x32_fp8_fp8(a, bv, acc, 0, 0, 0);
        }
        if (col < 2) s_acc[w][g * 2 + col] = acc;
        __syncthreads();

        // ---- finalize rows (all writers in wave 0) ----
        if (t < 16) {
            const int gg = (t >> 2) * 2, rr = t & 3;
            float S1 = 0.f, S2 = 0.f;
            #pragma unroll
            for (int ww = 0; ww < 4; ++ww) {
                S1 += s_acc[ww][gg + 0][rr];
                S2 += s_acc[ww][gg + 1][rr];
            }
            const float ti = s_th[t];
            float si, ci;
            sincosf(ti, &si, &ci);
            const float csum = si * S1 - ci * S2;
            const float th = fmodf(ti + DT * (om + K_OVER_N * csum), TWO_PI_F);
            s_th[t] = th;
            const size_t bi = (size_t)b * N + rt * 16 + t;
            if (s == STEPS - 1) {
                out[bi] = th;
            } else {
                float sn, cn;
                sincosf(th, &sn, &cn);
                unsigned char* tO = (((s + 1) & 1) ? tbl1 : tbl0) + (size_t)b * 4096;
                tO[rt * 16 + t] = f2fp8(cn);
                tO[2048 + rt * 16 + t] = f2fp8(sn);
            }
        }
        // ---- publish: writers are wave 0; lane 0 releases + signals ----
        if (s < STEPS - 1 && t == 0) {
            __builtin_amdgcn_fence(__ATOMIC_RELEASE, "agent");
            __hip_atomic_fetch_add(&cnt[b], 1u, __ATOMIC_RELAXED,
                                   __HIP_MEMORY_SCOPE_AGENT);
        }
    }
}

extern "C" void kernel_launch(void* const* d_in, const int* in_sizes, int n_in,
                              void* d_out, int out_size, void* d_ws, size_t ws_size,
                              hipStream_t stream) {
    const float* theta0 = (const float*)d_in[0];  // [B,N]
    const float* emb    = (const float*)d_in[1];  // [B,N,D]
    const float* omega  = (const float*)d_in[2];  // [N]
    float* out = (float*)d_out;                   // [B,N]

    // workspace layout (~42 MiB)
    unsigned short* En = (unsigned short*)d_ws;                    // B*N*D bf16
    unsigned char*  C  = (unsigned char*)(En + (size_t)B * N * D); // B*N*N fp8
    unsigned char* tb0 = C + (size_t)B * N * N;                    // B*4096 fp8
    unsigned char* tb1 = tb0 + (size_t)B * 4096;                   // B*4096 fp8
    unsigned int*  cnt = (unsigned int*)(tb1 + (size_t)B * 4096);  // B u32

    (void)hipMemsetAsync(cnt, 0, B * sizeof(unsigned int), stream);

    normalize_k<<<B * N / 4, 256, 0, stream>>>(emb, En);

    dim3 gC(N / 64, N / 64, B);
    build_c_k<<<gC, 256, 0, stream>>>(En, C);

    init_tbl_k<<<B * N / 256, 256, 0, stream>>>(theta0, tb0);

    fused_steps_k<<<dim3(N / 16, B), 256, 0, stream>>>(C, tb0, tb1, theta0,
                                                       out, omega, cnt);
}

// Round 7
// 403.356 us; speedup vs baseline: 12.1850x; 12.1850x over previous
//
#include <hip/hip_runtime.h>
#include <hip/hip_bf16.h>

// Kuramoto V2: B=8, N=2048, D=256, 50 steps.
//  1) normalize embeddings -> bf16 En
//  2) C = clip(En En^T, 0) -> fp8 e4m3 row-major (symmetric-store trick)
//  3) ONE persistent kernel: each block owns 64 rows of C in 128KB LDS
//     (staged once, XOR-swizzled), iterates all 50 steps. Per-batch sync =
//     padded monotonic counter, 32 participants, s_sleep(8) backoff spin.
//     (R5 lesson: 1024 spinners on ONE cacheline = ~96us/step. Now 32
//      spinners per 256B-padded line.)
// R7 = byte-identical resubmit of R6 (R6 failed with the same
// UnresponsiveContainer infra error as the untouched R0 stub).

constexpr int B = 8;
constexpr int N = 2048;
constexpr int D = 256;
constexpr int STEPS = 50;
constexpr int ROWS = 64;            // C-rows per block
constexpr int BPB  = 32;            // blocks per batch
constexpr int TPB  = 512;           // threads per block (8 waves)
constexpr float DT = 0.01f;
constexpr float K_OVER_N = 1.0f / 2048.0f;
constexpr float TWO_PI_F = 6.2831854820251465f; // float(2*pi)

using bf16x8 = __attribute__((ext_vector_type(8))) short;
using f32x4  = __attribute__((ext_vector_type(4))) float;

static __device__ __forceinline__ unsigned short f2bf(float f) {
    union { float f; unsigned int i; } v; v.f = f;
    unsigned int x = v.i;
    x += 0x7fffu + ((x >> 16) & 1u);   // RNE
    return (unsigned short)(x >> 16);
}
static __device__ __forceinline__ unsigned char f2fp8(float f) {
    return (unsigned char)(__builtin_amdgcn_cvt_pk_fp8_f32(f, f, 0, false) & 0xff);
}

// ---------------- normalize: one wave per row of 256 floats -> bf16 -------
__global__ void normalize_k(const float* __restrict__ emb,
                            unsigned short* __restrict__ En) {
    const int row  = blockIdx.x * 4 + (threadIdx.x >> 6);
    const int lane = threadIdx.x & 63;
    const float4 v = *(const float4*)(emb + (size_t)row * D + lane * 4);
    float ss = v.x * v.x + v.y * v.y + v.z * v.z + v.w * v.w;
    #pragma unroll
    for (int k = 32; k >= 1; k >>= 1) ss += __shfl_xor(ss, k);
    const float inv = 1.0f / fmaxf(sqrtf(ss), 1e-12f);
    ushort4 o;
    o.x = f2bf(v.x * inv); o.y = f2bf(v.y * inv);
    o.z = f2bf(v.z * inv); o.w = f2bf(v.w * inv);
    *(ushort4*)(En + (size_t)row * D + lane * 4) = o;
}

// ---------------- build C = clip(En En^T, 0) -> fp8 row-major --------------
// C/D frag: col = lane&15, row = (lane>>4)*4 + reg; store transposed (C sym).
__global__ __launch_bounds__(256) void build_c_k(const unsigned short* __restrict__ En,
                                                 unsigned char* __restrict__ C) {
    const int b = blockIdx.z;
    const unsigned short* Eb = En + (size_t)b * N * D;
    const int wid  = threadIdx.x >> 6;
    const int lane = threadIdx.x & 63;
    const int i_base = blockIdx.y * 64 + (wid >> 1) * 32;
    const int j_base = blockIdx.x * 64 + (wid & 1) * 32;
    const int fr = lane & 15;
    const int fk = (lane >> 4) * 8;

    f32x4 acc[2][2];
    #pragma unroll
    for (int m = 0; m < 2; ++m)
        #pragma unroll
        for (int n = 0; n < 2; ++n)
            acc[m][n] = (f32x4){0.f, 0.f, 0.f, 0.f};

    for (int k0 = 0; k0 < D; k0 += 32) {
        bf16x8 a[2], bv[2];
        #pragma unroll
        for (int m = 0; m < 2; ++m)
            a[m] = *(const bf16x8*)(Eb + (size_t)(i_base + m * 16 + fr) * D + k0 + fk);
        #pragma unroll
        for (int n = 0; n < 2; ++n)
            bv[n] = *(const bf16x8*)(Eb + (size_t)(j_base + n * 16 + fr) * D + k0 + fk);
        #pragma unroll
        for (int m = 0; m < 2; ++m)
            #pragma unroll
            for (int n = 0; n < 2; ++n)
                acc[m][n] = __builtin_amdgcn_mfma_f32_16x16x32_bf16(a[m], bv[n], acc[m][n], 0, 0, 0);
    }

    unsigned char* Cb = C + (size_t)b * N * N;
    const int orow = (lane >> 4) * 4;
    #pragma unroll
    for (int m = 0; m < 2; ++m)
        #pragma unroll
        for (int n = 0; n < 2; ++n) {
            int w = __builtin_amdgcn_cvt_pk_fp8_f32(fmaxf(acc[m][n][0], 0.f),
                                                    fmaxf(acc[m][n][1], 0.f), 0, false);
            w = __builtin_amdgcn_cvt_pk_fp8_f32(fmaxf(acc[m][n][2], 0.f),
                                                fmaxf(acc[m][n][3], 0.f), w, true);
            const int j = j_base + n * 16 + fr;
            const int i = i_base + m * 16 + orow;
            *(unsigned int*)(Cb + (size_t)j * N + i) = (unsigned int)w;
        }
}

// ---------------- init tables: fp8 cos/sin of theta0 -----------------------
// layout: tbl[b*4096 + 0..2047] = cos, tbl[b*4096 + 2048..4095] = sin
__global__ void init_tbl_k(const float* __restrict__ theta,
                           unsigned char* __restrict__ tbl) {
    const int idx = blockIdx.x * 256 + threadIdx.x;   // 0..B*N-1
    const int b = idx >> 11, i = idx & 2047;
    float s, c;
    sincosf(theta[idx], &s, &c);
    tbl[(size_t)b * 4096 + i] = f2fp8(c);
    tbl[(size_t)b * 4096 + 2048 + i] = f2fp8(s);
}

// ---------------- persistent 50-step kernel --------------------------------
// Block = 64 rows of one batch, 8 waves: row-group grp = w>>1 (16 rows),
// K-half kh = w&1 (1024). C rows in LDS (swizzled) for all 50 steps.
__global__ __launch_bounds__(512, 2) void fused_steps_k(
        const unsigned char* __restrict__ C,
        unsigned char* __restrict__ tbl0,
        unsigned char* __restrict__ tbl1,
        const float* __restrict__ theta0,
        float* __restrict__ out,
        const float* __restrict__ omega,
        unsigned int* __restrict__ cnt) {
    __shared__ unsigned char s_C[ROWS * 2048];     // 128 KB, swizzled
    __shared__ unsigned char s_tbl[2080 + 2048];   // cos | pad32 | sin
    __shared__ f32x4 s_acc[8][8];                  // [wave][g*2+col]
    __shared__ float s_th[ROWS];

    const int rt = blockIdx.x;        // 0..31: rows rt*64..rt*64+63
    const int b  = blockIdx.y;
    const int t  = threadIdx.x;
    const int w = t >> 6, lane = t & 63;
    const int col = lane & 15, g = lane >> 4;
    const int grp = w >> 1, kh = w & 1;

    // ---- stage my 64 C-rows into LDS once, XOR-swizzle 16B units ----
    {
        const unsigned char* src = C + ((size_t)b * N + rt * ROWS) * N;
        #pragma unroll
        for (int it = 0; it < 16; ++it) {
            const int idx = it * TPB + t;        // 16B-unit index, 0..8191
            const int row = idx >> 7;            // 128 units per 2048B row
            const int o   = (idx & 127) * 16;
            const uint4 v = *(const uint4*)(src + (size_t)row * N + o);
            *(uint4*)(s_C + row * 2048 + (o ^ ((row & 7) << 4))) = v;
        }
    }
    if (t < ROWS) s_th[t] = theta0[(size_t)b * N + rt * ROWS + t];
    const float om = (t < ROWS) ? omega[rt * ROWS + t] : 0.f;

    const unsigned char* Abase = s_C + (grp * 16 + col) * 2048;
    const unsigned int sw = (unsigned)((col & 7) << 4);
    const int tblbase = (col == 1) ? 2080 : 0;    // col1 -> sin; else cos
    const int o0 = kh * 1024 + g * 8;
    unsigned int* mycnt = &cnt[b * 64];           // 256B-padded counters

    for (int s = 0; s < STEPS; ++s) {
        if (s > 0) {
            if (t == 0) {
                const unsigned int target = (unsigned)(BPB * s);
                while (__hip_atomic_load(mycnt, __ATOMIC_RELAXED,
                                         __HIP_MEMORY_SCOPE_AGENT) < target)
                    __builtin_amdgcn_s_sleep(8);   // ~512cy backoff
                __builtin_amdgcn_fence(__ATOMIC_ACQUIRE, "agent");
            }
            __syncthreads();
        }
        // ---- stage this step's tables (4 KB) ----
        const unsigned char* tI = ((s & 1) ? tbl1 : tbl0) + (size_t)b * 4096;
        if (t < 128)
            *(uint4*)(s_tbl + t * 16) = *(const uint4*)(tI + t * 16);
        else if (t < 256) {
            const int u = t - 128;
            *(uint4*)(s_tbl + 2080 + u * 16) = *(const uint4*)(tI + 2048 + u * 16);
        }
        __syncthreads();

        // ---- dual matvec via fp8 MFMA, A from swizzled LDS, 2-acc ILP ----
        f32x4 acc0 = {0.f, 0.f, 0.f, 0.f}, acc1 = {0.f, 0.f, 0.f, 0.f};
        #pragma unroll
        for (int u = 0; u < 32; u += 2) {
            const int oa = o0 + u * 32;
            const long a0 = *(const long*)(Abase + (oa ^ sw));
            const long a1 = *(const long*)(Abase + ((oa + 32) ^ sw));
            long b0 = *(const long*)(s_tbl + tblbase + oa);
            long b1 = *(const long*)(s_tbl + tblbase + oa + 32);
            b0 = (col < 2) ? b0 : 0L;
            b1 = (col < 2) ? b1 : 0L;
            acc0 = __builtin_amdgcn_mfma_f32_16x16x32_fp8_fp8(a0, b0, acc0, 0, 0, 0);
            acc1 = __builtin_amdgcn_mfma_f32_16x16x32_fp8_fp8(a1, b1, acc1, 0, 0, 0);
        }
        acc0 += acc1;
        if (col < 2) s_acc[w][g * 2 + col] = acc0;
        __syncthreads();

        // ---- finalize rows (64 writers, all in wave 0) ----
        if (t < ROWS) {
            const int gr = t >> 4;                   // row-group
            const int gg = ((t & 15) >> 2) * 2;      // s_acc slot base
            const int rr = t & 3;                    // reg within frag
            float S1 = 0.f, S2 = 0.f;
            #pragma unroll
            for (int h = 0; h < 2; ++h) {            // two K-halves
                S1 += s_acc[gr * 2 + h][gg + 0][rr];
                S2 += s_acc[gr * 2 + h][gg + 1][rr];
            }
            const float ti = s_th[t];
            float si, ci;
            sincosf(ti, &si, &ci);
            const float csum = si * S1 - ci * S2;
            const float th = fmodf(ti + DT * (om + K_OVER_N * csum), TWO_PI_F);
            s_th[t] = th;
            const size_t bi = (size_t)b * N + rt * ROWS + t;
            if (s == STEPS - 1) {
                out[bi] = th;
            } else {
                float sn, cn;
                sincosf(th, &sn, &cn);
                unsigned char* tO = (((s + 1) & 1) ? tbl1 : tbl0) + (size_t)b * 4096;
                tO[rt * ROWS + t] = f2fp8(cn);
                tO[2048 + rt * ROWS + t] = f2fp8(sn);
            }
        }
        // ---- publish (writers are wave 0; lane 0's fence covers the wave) --
        if (s < STEPS - 1 && t == 0) {
            __builtin_amdgcn_fence(__ATOMIC_RELEASE, "agent");
            __hip_atomic_fetch_add(mycnt, 1u, __ATOMIC_RELAXED,
                                   __HIP_MEMORY_SCOPE_AGENT);
        }
    }
}

extern "C" void kernel_launch(void* const* d_in, const int* in_sizes, int n_in,
                              void* d_out, int out_size, void* d_ws, size_t ws_size,
                              hipStream_t stream) {
    const float* theta0 = (const float*)d_in[0];  // [B,N]
    const float* emb    = (const float*)d_in[1];  // [B,N,D]
    const float* omega  = (const float*)d_in[2];  // [N]
    float* out = (float*)d_out;                   // [B,N]

    // workspace layout (~42 MiB)
    unsigned short* En = (unsigned short*)d_ws;                    // B*N*D bf16
    unsigned char*  C  = (unsigned char*)(En + (size_t)B * N * D); // B*N*N fp8
    unsigned char* tb0 = C + (size_t)B * N * N;                    // B*4096 fp8
    unsigned char* tb1 = tb0 + (size_t)B * 4096;                   // B*4096 fp8
    unsigned int*  cnt = (unsigned int*)(tb1 + (size_t)B * 4096);  // B*64 u32

    (void)hipMemsetAsync(cnt, 0, B * 64 * sizeof(unsigned int), stream);

    normalize_k<<<B * N / 4, 256, 0, stream>>>(emb, En);

    dim3 gC(N / 64, N / 64, B);
    build_c_k<<<gC, 256, 0, stream>>>(En, C);

    init_tbl_k<<<B * N / 256, 256, 0, stream>>>(theta0, tb0);

    fused_steps_k<<<dim3(BPB, B), TPB, 0, stream>>>(C, tb0, tb1, theta0,
                                                    out, omega, cnt);
}